// Round 10
// baseline (212.038 us; speedup 1.0000x reference)
//
#include <hip/hip_runtime.h>

// Shapes (fixed):
//   prev/next: [8, 32, 48, 48, 48] f32
//   phi:       [8, 1, 96, 96, 96] f32
//   stream:    [8, 3, 96, 96, 96] f32
// Outputs concatenated in d_out (f32): corr [8,27,48^3], vel/vel_phi/vel_stream [8,3,94^3]
//
// Model (R8-confirmed, R9-refined): wall = wave-vmem-instruction issue
// (~24 cy/instr) PROVIDED each access is naturally aligned (no line splits)
// and VGPR bin / block count keep CUs fed. R9's unaligned windows inflated
// FETCH +35MB and regressed. R10: vel t-block4 with ALL loads aligned
// (f4 at t%4==0 + f2/scalar tails): 45 vmem per 4 outputs vs 45 per 2.
// corr = R8 unchanged. nt stores kept.

typedef float f2 __attribute__((ext_vector_type(2)));
typedef float f4 __attribute__((ext_vector_type(4)));
typedef float f4u __attribute__((ext_vector_type(4), aligned(8)));   // stores: oo always even -> 8B

constexpr int CB = 8, CC = 32, CX = 48, CY = 48, CZ = 48;
constexpr int H = 96, O = 94;
constexpr int PLANE = CY * CZ;       // 2304
constexpr int CSTR  = CX * PLANE;    // 110592
constexpr int HP    = H * H;         // 9216
constexpr size_t O3 = (size_t)O * O * O;

constexpr int CORR_NWG   = (CB * CX * CY * (CZ / 4)) / 256;   // 864
constexpr int VELM_TOTAL = CB * O * O * 23;                   // 1,625,824 (t=0..91)
constexpr int VELM_NWG   = (VELM_TOTAL + 255) / 256;          // 6351
constexpr int VELT_TOTAL = CB * O * O;                        // 70,688 (t=92,93)
constexpr int VELT_NWG   = (VELT_TOTAL + 255) / 256;          // 277

// ---------------------------------------------------------------------------
// corr (R8, unchanged): thread owns (b,x,y,z4*4..+3); 10 f4 loads per c-step.
// ---------------------------------------------------------------------------
__device__ __forceinline__ void corr_body(
    int bid, const float* __restrict__ prev, const float* __restrict__ nxt,
    float* __restrict__ corr)
{
    constexpr int Z4 = CZ / 4;                       // 12
    int swz = (bid & 7) * (CORR_NWG / 8) + (bid >> 3);
    int idx = swz * 256 + (int)threadIdx.x;
    int z4 = idx % Z4; int r = idx / Z4;
    int y = r % CY; r /= CY;
    int x = r % CX; int b = r / CX;

    const size_t bbase = (size_t)b * CC * CSTR;
    const float* __restrict__ nbase = nxt + bbase;
    const float* pp = prev + bbase + (size_t)x * PLANE + (size_t)y * CZ + z4 * 4;

    const float* tp[9];
    float scj[9];
#pragma unroll
    for (int a = 0; a < 3; ++a) {
        int xx = x + a - 1;
        bool vx = (unsigned)xx < (unsigned)CX;
#pragma unroll
        for (int d = 0; d < 3; ++d) {
            int yy = y + d - 1;
            bool ok = vx && ((unsigned)yy < (unsigned)CY);
            tp[a * 3 + d] = nbase + (size_t)(ok ? xx : x) * PLANE
                                  + (size_t)(ok ? yy : y) * CZ + z4 * 4;
            scj[a * 3 + d] = ok ? (1.0f / 32.0f) : 0.0f;
        }
    }

    f4 acc[9];
#pragma unroll
    for (int jj = 0; jj < 9; ++jj) acc[jj] = f4{0.f, 0.f, 0.f, 0.f};

#pragma unroll 2
    for (int c = 0; c < CC; ++c) {
        f4 pv = *reinterpret_cast<const f4*>(pp);
#pragma unroll
        for (int jj = 0; jj < 9; ++jj) {
            f4 nv = *reinterpret_cast<const f4*>(tp[jj]);
            acc[jj] += pv * nv;
            tp[jj] += CSTR;
        }
        pp += CSTR;
    }

    const size_t obase = (size_t)b * 27 * CSTR + (size_t)x * PLANE
                       + (size_t)y * CZ + z4 * 4;
#pragma unroll
    for (int jj = 0; jj < 9; ++jj) {
        f4 v = acc[jj] * scj[jj];
        f4 gm = v; if (z4 == Z4 - 1) gm.w = 0.f;     // k=-1: zero z==47
        f4 gp = v; if (z4 == 0)      gp.x = 0.f;     // k=+1: zero z==0
        __builtin_nontemporal_store(gm, (f4*)(corr + obase + (size_t)jj * CSTR));
        __builtin_nontemporal_store(v,  (f4*)(corr + obase + (size_t)(9 + jj) * CSTR));
        __builtin_nontemporal_store(gp, (f4*)(corr + obase + (size_t)(18 + jj) * CSTR));
    }
}

// Row helpers — ALL component loads naturally aligned (base 16B-aligned).
struct R6 { f4 a; f2 b; };     // elems 0..5: f4 + 8B-aligned f2
struct R5 { f4 a; float e; };  // elems 0..4: f4 + scalar
__device__ __forceinline__ R6 ld6(const float* p) {
    R6 r; r.a = *reinterpret_cast<const f4*>(p);
    r.b = *reinterpret_cast<const f2*>(p + 4); return r;
}
__device__ __forceinline__ R5 ld5(const float* p) {
    R5 r; r.a = *reinterpret_cast<const f4*>(p); r.e = p[4]; return r;
}
#define E6(r, k) ((k) < 4 ? (r).a[(k)] : (r).b[(k) - 4])
#define E5(r, k) ((k) < 4 ? (r).a[(k)] : (r).e)

__device__ __forceinline__ void velm_body(
    int bid, const float* __restrict__ phi, const float* __restrict__ stm,
    float* __restrict__ vel, float* __restrict__ vphi, float* __restrict__ vstr)
{
    const int q = VELM_NWG >> 3, rr = VELM_NWG & 7;  // 793, 7
    int xcd = bid & 7, g = bid >> 3;
    int swz = (xcd < rr) ? (xcd * (q + 1) + g) : (rr * (q + 1) + (xcd - rr) * q + g);
    int idx = swz * 256 + (int)threadIdx.x;
    if (idx >= VELM_TOTAL) return;
    int tt = idx % 23; int r2 = idx / 23;
    int j = r2 % O; r2 /= O;
    int i = r2 % O; int b = r2 / O;
    const int t = 4 * tt;                            // t % 4 == 0 -> 16B-aligned f4

    const size_t hc = (size_t)H * HP;
    const float* ph = phi + (size_t)b * hc;
    const float* s0 = stm + (size_t)b * 3 * hc;
    const float* s1 = s0 + hc;
    const float* s2 = s1 + hc;
    const size_t ctr = (size_t)(i + 1) * HP + (size_t)(j + 1) * H + t;

    const size_t oo = ((size_t)i * O + j) * O + t;   // always even -> 8B-aligned stores
    const size_t b3 = (size_t)b * 3;

    // ---- phi phase (10 loads, 3 stores) ----
    R6 c11 = ld6(ph + ctr);
    R5 r12 = ld5(ph + ctr + H);
    R5 r10 = ld5(ph + ctr - H);
    R5 r21 = ld5(ph + ctr + HP);
    R5 r01 = ld5(ph + ctr - HP);
    float mup[4], mvp[4], mwp[4];
#pragma unroll
    for (int o = 0; o < 4; ++o) {
        mup[o] = (E6(c11, o + 2) - E6(c11, o)) * 0.5f;
        mvp[o] = (E5(r12, o + 1) - E5(r10, o + 1)) * 0.5f;
        mwp[o] = (E5(r21, o + 1) - E5(r01, o + 1)) * 0.5f;
    }
    __builtin_nontemporal_store(f4u{mup[0], mup[1], mup[2], mup[3]}, (f4u*)(vphi + (b3 + 0) * O3 + oo));
    __builtin_nontemporal_store(f4u{mvp[0], mvp[1], mvp[2], mvp[3]}, (f4u*)(vphi + (b3 + 1) * O3 + oo));
    __builtin_nontemporal_store(f4u{mwp[0], mwp[1], mwp[2], mwp[3]}, (f4u*)(vphi + (b3 + 2) * O3 + oo));

    // ---- u = d_x s1 - d_y s0 (8 loads, 2 stores); A1_11/A0_11 stay live ----
    R5 A1_21 = ld5(s1 + ctr + HP);
    R6 A1_11 = ld6(s1 + ctr);
    R5 A0_12 = ld5(s0 + ctr + H);
    R6 A0_11 = ld6(s0 + ctr);
    float u[5];
#pragma unroll
    for (int k = 0; k < 5; ++k)
        u[k] = (E5(A1_21, k) - E6(A1_11, k)) - (E5(A0_12, k) - E6(A0_11, k));
    float mus[4];
#pragma unroll
    for (int o = 0; o < 4; ++o) mus[o] = (u[o + 1] + u[o]) * 0.5f;
    __builtin_nontemporal_store(f4u{mus[0], mus[1], mus[2], mus[3]}, (f4u*)(vstr + (b3 + 0) * O3 + oo));
    __builtin_nontemporal_store(f4u{mup[0] + mus[0], mup[1] + mus[1], mup[2] + mus[2], mup[3] + mus[3]},
                                (f4u*)(vel + (b3 + 0) * O3 + oo));

    // ---- v = d_t s0 - d_x s2 (10 loads, 2 stores); B2_11 stays live ----
    R6 B0_10 = ld6(s0 + ctr - H);
    R5 B2_21 = ld5(s2 + ctr + HP);
    R5 B2_11 = ld5(s2 + ctr);
    R5 B2_20 = ld5(s2 + ctr + HP - H);
    R5 B2_10 = ld5(s2 + ctr - H);
    float mvs[4];
#pragma unroll
    for (int o = 0; o < 4; ++o) {
        float v1 = (E6(A0_11, o + 2) - E6(A0_11, o + 1)) - (E5(B2_21, o + 1) - E5(B2_11, o + 1));
        float v0 = (E6(B0_10, o + 2) - E6(B0_10, o + 1)) - (E5(B2_20, o + 1) - E5(B2_10, o + 1));
        mvs[o] = (v1 + v0) * 0.5f;
    }
    __builtin_nontemporal_store(f4u{mvs[0], mvs[1], mvs[2], mvs[3]}, (f4u*)(vstr + (b3 + 1) * O3 + oo));
    __builtin_nontemporal_store(f4u{mvp[0] + mvs[0], mvp[1] + mvs[1], mvp[2] + mvs[2], mvp[3] + mvs[3]},
                                (f4u*)(vel + (b3 + 1) * O3 + oo));

    // ---- w = d_y s2 - d_t s1 (8 loads, 2 stores) ----
    R5 C2_12 = ld5(s2 + ctr + H);
    R5 C2_02 = ld5(s2 + ctr - HP + H);
    R5 C2_01 = ld5(s2 + ctr - HP);
    R6 C1_01 = ld6(s1 + ctr - HP);
    float mws[4];
#pragma unroll
    for (int o = 0; o < 4; ++o) {
        float w1 = (E5(C2_12, o + 1) - E5(B2_11, o + 1)) - (E6(A1_11, o + 2) - E6(A1_11, o + 1));
        float w0 = (E5(C2_02, o + 1) - E5(C2_01, o + 1)) - (E6(C1_01, o + 2) - E6(C1_01, o + 1));
        mws[o] = (w1 + w0) * 0.5f;
    }
    __builtin_nontemporal_store(f4u{mws[0], mws[1], mws[2], mws[3]}, (f4u*)(vstr + (b3 + 2) * O3 + oo));
    __builtin_nontemporal_store(f4u{mwp[0] + mws[0], mwp[1] + mws[1], mwp[2] + mws[2], mwp[3] + mws[3]},
                                (f4u*)(vel + (b3 + 2) * O3 + oo));
}

// ---------------------------------------------------------------------------
// vel tail: t = 92,93. Windows 92..95 -> one aligned f4 per row (proven R4/R9).
// ---------------------------------------------------------------------------
__device__ __forceinline__ void velt_body(
    int bid, const float* __restrict__ phi, const float* __restrict__ stm,
    float* __restrict__ vel, float* __restrict__ vphi, float* __restrict__ vstr)
{
    int idx = bid * 256 + (int)threadIdx.x;
    if (idx >= VELT_TOTAL) return;
    int j = idx % O; int r2 = idx / O;
    int i = r2 % O; int b = r2 / O;
    const int t = 92;

    const size_t hc = (size_t)H * HP;
    const float* ph = phi + (size_t)b * hc;
    const float* s0 = stm + (size_t)b * 3 * hc;
    const float* s1 = s0 + hc;
    const float* s2 = s1 + hc;
    const size_t ctr = (size_t)(i + 1) * HP + (size_t)(j + 1) * H + t;

#define L4(p) (*reinterpret_cast<const f4*>(p))
    f4 c11 = L4(ph + ctr), r12 = L4(ph + ctr + H), r10 = L4(ph + ctr - H);
    f4 r21 = L4(ph + ctr + HP), r01 = L4(ph + ctr - HP);
    f4 b1_21 = L4(s1 + ctr + HP), b1_11 = L4(s1 + ctr), b1_01 = L4(s1 + ctr - HP);
    f4 b0_12 = L4(s0 + ctr + H), b0_11 = L4(s0 + ctr), b0_10 = L4(s0 + ctr - H);
    f4 b2_21 = L4(s2 + ctr + HP), b2_11 = L4(s2 + ctr), b2_20 = L4(s2 + ctr + HP - H);
    f4 b2_10 = L4(s2 + ctr - H), b2_12 = L4(s2 + ctr + H), b2_02 = L4(s2 + ctr - HP + H);
    f4 b2_01 = L4(s2 + ctr - HP);
#undef L4

    float mup[2], mvp[2], mwp[2], mus[2], mvs[2], mws[2];
    float u[3];
#pragma unroll
    for (int k = 0; k < 3; ++k)
        u[k] = (b1_21[k] - b1_11[k]) - (b0_12[k] - b0_11[k]);
#pragma unroll
    for (int o = 0; o < 2; ++o) {
        mup[o] = (c11[o + 2] - c11[o]) * 0.5f;
        mvp[o] = (r12[o + 1] - r10[o + 1]) * 0.5f;
        mwp[o] = (r21[o + 1] - r01[o + 1]) * 0.5f;
        mus[o] = (u[o + 1] + u[o]) * 0.5f;
        float v1 = (b0_11[o + 2] - b0_11[o + 1]) - (b2_21[o + 1] - b2_11[o + 1]);
        float v0 = (b0_10[o + 2] - b0_10[o + 1]) - (b2_20[o + 1] - b2_10[o + 1]);
        mvs[o] = (v1 + v0) * 0.5f;
        float w1 = (b2_12[o + 1] - b2_11[o + 1]) - (b1_11[o + 2] - b1_11[o + 1]);
        float w0 = (b2_02[o + 1] - b2_01[o + 1]) - (b1_01[o + 2] - b1_01[o + 1]);
        mws[o] = (w1 + w0) * 0.5f;
    }

    const size_t oo = ((size_t)i * O + j) * O + t;
    const size_t b3 = (size_t)b * 3;
    __builtin_nontemporal_store(f2{mup[0], mup[1]}, (f2*)(vphi + (b3 + 0) * O3 + oo));
    __builtin_nontemporal_store(f2{mvp[0], mvp[1]}, (f2*)(vphi + (b3 + 1) * O3 + oo));
    __builtin_nontemporal_store(f2{mwp[0], mwp[1]}, (f2*)(vphi + (b3 + 2) * O3 + oo));
    __builtin_nontemporal_store(f2{mus[0], mus[1]}, (f2*)(vstr + (b3 + 0) * O3 + oo));
    __builtin_nontemporal_store(f2{mvs[0], mvs[1]}, (f2*)(vstr + (b3 + 1) * O3 + oo));
    __builtin_nontemporal_store(f2{mws[0], mws[1]}, (f2*)(vstr + (b3 + 2) * O3 + oo));
    __builtin_nontemporal_store(f2{mup[0] + mus[0], mup[1] + mus[1]}, (f2*)(vel + (b3 + 0) * O3 + oo));
    __builtin_nontemporal_store(f2{mvp[0] + mvs[0], mvp[1] + mvs[1]}, (f2*)(vel + (b3 + 1) * O3 + oo));
    __builtin_nontemporal_store(f2{mwp[0] + mws[0], mwp[1] + mws[1]}, (f2*)(vel + (b3 + 2) * O3 + oo));
}

__global__ __launch_bounds__(256) void fused_kernel(
    const float* __restrict__ prev, const float* __restrict__ nxt,
    const float* __restrict__ phi, const float* __restrict__ stm,
    float* __restrict__ corr, float* __restrict__ vel,
    float* __restrict__ vphi, float* __restrict__ vstr)
{
    int bid = blockIdx.x;
    if (bid < CORR_NWG) {
        corr_body(bid, prev, nxt, corr);
    } else if (bid < CORR_NWG + VELM_NWG) {
        velm_body(bid - CORR_NWG, phi, stm, vel, vphi, vstr);
    } else {
        velt_body(bid - CORR_NWG - VELM_NWG, phi, stm, vel, vphi, vstr);
    }
}

extern "C" void kernel_launch(void* const* d_in, const int* in_sizes, int n_in,
                              void* d_out, int out_size, void* d_ws, size_t ws_size,
                              hipStream_t stream)
{
    const float* prev = (const float*)d_in[0];
    const float* nxt  = (const float*)d_in[1];
    const float* phi  = (const float*)d_in[2];
    const float* stm  = (const float*)d_in[3];

    float* out = (float*)d_out;
    const size_t corr_sz = (size_t)CB * 27 * CX * CY * CZ;   // 23,887,872
    const size_t vel_sz  = (size_t)CB * 3 * O * O * O;       // 19,934,016
    float* corr = out;
    float* vel  = out + corr_sz;
    float* vphi = vel + vel_sz;
    float* vstr = vphi + vel_sz;

    fused_kernel<<<CORR_NWG + VELM_NWG + VELT_NWG, 256, 0, stream>>>(
        prev, nxt, phi, stm, corr, vel, vphi, vstr);
}

// Round 11
// 211.318 us; speedup vs baseline: 1.0034x; 1.0034x over previous
//
#include <hip/hip_runtime.h>

// Shapes (fixed):
//   prev/next: [8, 32, 48, 48, 48] f32
//   phi:       [8, 1, 96, 96, 96] f32
//   stream:    [8, 3, 96, 96, 96] f32
// Outputs concatenated in d_out (f32): corr [8,27,48^3], vel/vel_phi/vel_stream [8,3,94^3]
//
// Model v3: wall = wave-vmem-instruction issue (~24 cy) where each access is
// naturally aligned AND doesn't partial-fill sectors. R9/R10 showed 16B nt
// stores at 8B-not-16B alignment cause RMW (+35MB FETCH, +19MB WRITE) and
// regress. R11 = R10's aligned t-block4 loads + CLEAN 8B f2 stores (2 per
// row). 54 vmem / 4 outputs vs R8's 90. corr = R8 unchanged.

typedef float f2 __attribute__((ext_vector_type(2)));
typedef float f4 __attribute__((ext_vector_type(4)));

constexpr int CB = 8, CC = 32, CX = 48, CY = 48, CZ = 48;
constexpr int H = 96, O = 94;
constexpr int PLANE = CY * CZ;       // 2304
constexpr int CSTR  = CX * PLANE;    // 110592
constexpr int HP    = H * H;         // 9216
constexpr size_t O3 = (size_t)O * O * O;

constexpr int CORR_NWG   = (CB * CX * CY * (CZ / 4)) / 256;   // 864
constexpr int VELM_TOTAL = CB * O * O * 23;                   // 1,625,824 (t=0..91)
constexpr int VELM_NWG   = (VELM_TOTAL + 255) / 256;          // 6351
constexpr int VELT_TOTAL = CB * O * O;                        // 70,688 (t=92,93)
constexpr int VELT_NWG   = (VELT_TOTAL + 255) / 256;          // 277

// ---------------------------------------------------------------------------
// corr (R8, unchanged): thread owns (b,x,y,z4*4..+3); 10 f4 loads per c-step.
// ---------------------------------------------------------------------------
__device__ __forceinline__ void corr_body(
    int bid, const float* __restrict__ prev, const float* __restrict__ nxt,
    float* __restrict__ corr)
{
    constexpr int Z4 = CZ / 4;                       // 12
    int swz = (bid & 7) * (CORR_NWG / 8) + (bid >> 3);
    int idx = swz * 256 + (int)threadIdx.x;
    int z4 = idx % Z4; int r = idx / Z4;
    int y = r % CY; r /= CY;
    int x = r % CX; int b = r / CX;

    const size_t bbase = (size_t)b * CC * CSTR;
    const float* __restrict__ nbase = nxt + bbase;
    const float* pp = prev + bbase + (size_t)x * PLANE + (size_t)y * CZ + z4 * 4;

    const float* tp[9];
    float scj[9];
#pragma unroll
    for (int a = 0; a < 3; ++a) {
        int xx = x + a - 1;
        bool vx = (unsigned)xx < (unsigned)CX;
#pragma unroll
        for (int d = 0; d < 3; ++d) {
            int yy = y + d - 1;
            bool ok = vx && ((unsigned)yy < (unsigned)CY);
            tp[a * 3 + d] = nbase + (size_t)(ok ? xx : x) * PLANE
                                  + (size_t)(ok ? yy : y) * CZ + z4 * 4;
            scj[a * 3 + d] = ok ? (1.0f / 32.0f) : 0.0f;
        }
    }

    f4 acc[9];
#pragma unroll
    for (int jj = 0; jj < 9; ++jj) acc[jj] = f4{0.f, 0.f, 0.f, 0.f};

#pragma unroll 2
    for (int c = 0; c < CC; ++c) {
        f4 pv = *reinterpret_cast<const f4*>(pp);
#pragma unroll
        for (int jj = 0; jj < 9; ++jj) {
            f4 nv = *reinterpret_cast<const f4*>(tp[jj]);
            acc[jj] += pv * nv;
            tp[jj] += CSTR;
        }
        pp += CSTR;
    }

    const size_t obase = (size_t)b * 27 * CSTR + (size_t)x * PLANE
                       + (size_t)y * CZ + z4 * 4;
#pragma unroll
    for (int jj = 0; jj < 9; ++jj) {
        f4 v = acc[jj] * scj[jj];
        f4 gm = v; if (z4 == Z4 - 1) gm.w = 0.f;     // k=-1: zero z==47
        f4 gp = v; if (z4 == 0)      gp.x = 0.f;     // k=+1: zero z==0
        __builtin_nontemporal_store(gm, (f4*)(corr + obase + (size_t)jj * CSTR));
        __builtin_nontemporal_store(v,  (f4*)(corr + obase + (size_t)(9 + jj) * CSTR));
        __builtin_nontemporal_store(gp, (f4*)(corr + obase + (size_t)(18 + jj) * CSTR));
    }
}

// Row helpers — ALL component loads naturally aligned (base 16B-aligned).
struct R6 { f4 a; f2 b; };     // elems 0..5: f4 + 8B-aligned f2
struct R5 { f4 a; float e; };  // elems 0..4: f4 + scalar
__device__ __forceinline__ R6 ld6(const float* p) {
    R6 r; r.a = *reinterpret_cast<const f4*>(p);
    r.b = *reinterpret_cast<const f2*>(p + 4); return r;
}
__device__ __forceinline__ R5 ld5(const float* p) {
    R5 r; r.a = *reinterpret_cast<const f4*>(p); r.e = p[4]; return r;
}
#define E6(r, k) ((k) < 4 ? (r).a[(k)] : (r).b[(k) - 4])
#define E5(r, k) ((k) < 4 ? (r).a[(k)] : (r).e)

// clean 16B-value store as two aligned 8B nt stores (oo always even)
__device__ __forceinline__ void st4(float* p, float v0, float v1, float v2, float v3) {
    __builtin_nontemporal_store(f2{v0, v1}, (f2*)p);
    __builtin_nontemporal_store(f2{v2, v3}, (f2*)(p + 2));
}

__device__ __forceinline__ void velm_body(
    int bid, const float* __restrict__ phi, const float* __restrict__ stm,
    float* __restrict__ vel, float* __restrict__ vphi, float* __restrict__ vstr)
{
    const int q = VELM_NWG >> 3, rr = VELM_NWG & 7;  // 793, 7
    int xcd = bid & 7, g = bid >> 3;
    int swz = (xcd < rr) ? (xcd * (q + 1) + g) : (rr * (q + 1) + (xcd - rr) * q + g);
    int idx = swz * 256 + (int)threadIdx.x;
    if (idx >= VELM_TOTAL) return;
    int tt = idx % 23; int r2 = idx / 23;
    int j = r2 % O; r2 /= O;
    int i = r2 % O; int b = r2 / O;
    const int t = 4 * tt;                            // t % 4 == 0 -> 16B-aligned f4

    const size_t hc = (size_t)H * HP;
    const float* ph = phi + (size_t)b * hc;
    const float* s0 = stm + (size_t)b * 3 * hc;
    const float* s1 = s0 + hc;
    const float* s2 = s1 + hc;
    const size_t ctr = (size_t)(i + 1) * HP + (size_t)(j + 1) * H + t;

    const size_t oo = ((size_t)i * O + j) * O + t;   // always even -> 8B-aligned f2 stores
    const size_t b3 = (size_t)b * 3;

    // ---- phi phase (10 loads, 6 stores) ----
    R6 c11 = ld6(ph + ctr);
    R5 r12 = ld5(ph + ctr + H);
    R5 r10 = ld5(ph + ctr - H);
    R5 r21 = ld5(ph + ctr + HP);
    R5 r01 = ld5(ph + ctr - HP);
    float mup[4], mvp[4], mwp[4];
#pragma unroll
    for (int o = 0; o < 4; ++o) {
        mup[o] = (E6(c11, o + 2) - E6(c11, o)) * 0.5f;
        mvp[o] = (E5(r12, o + 1) - E5(r10, o + 1)) * 0.5f;
        mwp[o] = (E5(r21, o + 1) - E5(r01, o + 1)) * 0.5f;
    }
    st4(vphi + (b3 + 0) * O3 + oo, mup[0], mup[1], mup[2], mup[3]);
    st4(vphi + (b3 + 1) * O3 + oo, mvp[0], mvp[1], mvp[2], mvp[3]);
    st4(vphi + (b3 + 2) * O3 + oo, mwp[0], mwp[1], mwp[2], mwp[3]);

    // ---- u = d_x s1 - d_y s0 (8 loads, 4 stores); A1_11/A0_11 stay live ----
    R5 A1_21 = ld5(s1 + ctr + HP);
    R6 A1_11 = ld6(s1 + ctr);
    R5 A0_12 = ld5(s0 + ctr + H);
    R6 A0_11 = ld6(s0 + ctr);
    float u[5];
#pragma unroll
    for (int k = 0; k < 5; ++k)
        u[k] = (E5(A1_21, k) - E6(A1_11, k)) - (E5(A0_12, k) - E6(A0_11, k));
    float mus[4];
#pragma unroll
    for (int o = 0; o < 4; ++o) mus[o] = (u[o + 1] + u[o]) * 0.5f;
    st4(vstr + (b3 + 0) * O3 + oo, mus[0], mus[1], mus[2], mus[3]);
    st4(vel + (b3 + 0) * O3 + oo, mup[0] + mus[0], mup[1] + mus[1],
                                  mup[2] + mus[2], mup[3] + mus[3]);

    // ---- v = d_t s0 - d_x s2 (10 loads, 4 stores); B2_11 stays live ----
    R6 B0_10 = ld6(s0 + ctr - H);
    R5 B2_21 = ld5(s2 + ctr + HP);
    R5 B2_11 = ld5(s2 + ctr);
    R5 B2_20 = ld5(s2 + ctr + HP - H);
    R5 B2_10 = ld5(s2 + ctr - H);
    float mvs[4];
#pragma unroll
    for (int o = 0; o < 4; ++o) {
        float v1 = (E6(A0_11, o + 2) - E6(A0_11, o + 1)) - (E5(B2_21, o + 1) - E5(B2_11, o + 1));
        float v0 = (E6(B0_10, o + 2) - E6(B0_10, o + 1)) - (E5(B2_20, o + 1) - E5(B2_10, o + 1));
        mvs[o] = (v1 + v0) * 0.5f;
    }
    st4(vstr + (b3 + 1) * O3 + oo, mvs[0], mvs[1], mvs[2], mvs[3]);
    st4(vel + (b3 + 1) * O3 + oo, mvp[0] + mvs[0], mvp[1] + mvs[1],
                                  mvp[2] + mvs[2], mvp[3] + mvs[3]);

    // ---- w = d_y s2 - d_t s1 (8 loads, 4 stores) ----
    R5 C2_12 = ld5(s2 + ctr + H);
    R5 C2_02 = ld5(s2 + ctr - HP + H);
    R5 C2_01 = ld5(s2 + ctr - HP);
    R6 C1_01 = ld6(s1 + ctr - HP);
    float mws[4];
#pragma unroll
    for (int o = 0; o < 4; ++o) {
        float w1 = (E5(C2_12, o + 1) - E5(B2_11, o + 1)) - (E6(A1_11, o + 2) - E6(A1_11, o + 1));
        float w0 = (E5(C2_02, o + 1) - E5(C2_01, o + 1)) - (E6(C1_01, o + 2) - E6(C1_01, o + 1));
        mws[o] = (w1 + w0) * 0.5f;
    }
    st4(vstr + (b3 + 2) * O3 + oo, mws[0], mws[1], mws[2], mws[3]);
    st4(vel + (b3 + 2) * O3 + oo, mwp[0] + mws[0], mwp[1] + mws[1],
                                  mwp[2] + mws[2], mwp[3] + mws[3]);
}

// ---------------------------------------------------------------------------
// vel tail: t = 92,93. Windows 92..95 -> one aligned f4 per row (proven).
// ---------------------------------------------------------------------------
__device__ __forceinline__ void velt_body(
    int bid, const float* __restrict__ phi, const float* __restrict__ stm,
    float* __restrict__ vel, float* __restrict__ vphi, float* __restrict__ vstr)
{
    int idx = bid * 256 + (int)threadIdx.x;
    if (idx >= VELT_TOTAL) return;
    int j = idx % O; int r2 = idx / O;
    int i = r2 % O; int b = r2 / O;
    const int t = 92;

    const size_t hc = (size_t)H * HP;
    const float* ph = phi + (size_t)b * hc;
    const float* s0 = stm + (size_t)b * 3 * hc;
    const float* s1 = s0 + hc;
    const float* s2 = s1 + hc;
    const size_t ctr = (size_t)(i + 1) * HP + (size_t)(j + 1) * H + t;

#define L4(p) (*reinterpret_cast<const f4*>(p))
    f4 c11 = L4(ph + ctr), r12 = L4(ph + ctr + H), r10 = L4(ph + ctr - H);
    f4 r21 = L4(ph + ctr + HP), r01 = L4(ph + ctr - HP);
    f4 b1_21 = L4(s1 + ctr + HP), b1_11 = L4(s1 + ctr), b1_01 = L4(s1 + ctr - HP);
    f4 b0_12 = L4(s0 + ctr + H), b0_11 = L4(s0 + ctr), b0_10 = L4(s0 + ctr - H);
    f4 b2_21 = L4(s2 + ctr + HP), b2_11 = L4(s2 + ctr), b2_20 = L4(s2 + ctr + HP - H);
    f4 b2_10 = L4(s2 + ctr - H), b2_12 = L4(s2 + ctr + H), b2_02 = L4(s2 + ctr - HP + H);
    f4 b2_01 = L4(s2 + ctr - HP);
#undef L4

    float mup[2], mvp[2], mwp[2], mus[2], mvs[2], mws[2];
    float u[3];
#pragma unroll
    for (int k = 0; k < 3; ++k)
        u[k] = (b1_21[k] - b1_11[k]) - (b0_12[k] - b0_11[k]);
#pragma unroll
    for (int o = 0; o < 2; ++o) {
        mup[o] = (c11[o + 2] - c11[o]) * 0.5f;
        mvp[o] = (r12[o + 1] - r10[o + 1]) * 0.5f;
        mwp[o] = (r21[o + 1] - r01[o + 1]) * 0.5f;
        mus[o] = (u[o + 1] + u[o]) * 0.5f;
        float v1 = (b0_11[o + 2] - b0_11[o + 1]) - (b2_21[o + 1] - b2_11[o + 1]);
        float v0 = (b0_10[o + 2] - b0_10[o + 1]) - (b2_20[o + 1] - b2_10[o + 1]);
        mvs[o] = (v1 + v0) * 0.5f;
        float w1 = (b2_12[o + 1] - b2_11[o + 1]) - (b1_11[o + 2] - b1_11[o + 1]);
        float w0 = (b2_02[o + 1] - b2_01[o + 1]) - (b1_01[o + 2] - b1_01[o + 1]);
        mws[o] = (w1 + w0) * 0.5f;
    }

    const size_t oo = ((size_t)i * O + j) * O + t;
    const size_t b3 = (size_t)b * 3;
    __builtin_nontemporal_store(f2{mup[0], mup[1]}, (f2*)(vphi + (b3 + 0) * O3 + oo));
    __builtin_nontemporal_store(f2{mvp[0], mvp[1]}, (f2*)(vphi + (b3 + 1) * O3 + oo));
    __builtin_nontemporal_store(f2{mwp[0], mwp[1]}, (f2*)(vphi + (b3 + 2) * O3 + oo));
    __builtin_nontemporal_store(f2{mus[0], mus[1]}, (f2*)(vstr + (b3 + 0) * O3 + oo));
    __builtin_nontemporal_store(f2{mvs[0], mvs[1]}, (f2*)(vstr + (b3 + 1) * O3 + oo));
    __builtin_nontemporal_store(f2{mws[0], mws[1]}, (f2*)(vstr + (b3 + 2) * O3 + oo));
    __builtin_nontemporal_store(f2{mup[0] + mus[0], mup[1] + mus[1]}, (f2*)(vel + (b3 + 0) * O3 + oo));
    __builtin_nontemporal_store(f2{mvp[0] + mvs[0], mvp[1] + mvs[1]}, (f2*)(vel + (b3 + 1) * O3 + oo));
    __builtin_nontemporal_store(f2{mwp[0] + mws[0], mwp[1] + mws[1]}, (f2*)(vel + (b3 + 2) * O3 + oo));
}

__global__ __launch_bounds__(256) void fused_kernel(
    const float* __restrict__ prev, const float* __restrict__ nxt,
    const float* __restrict__ phi, const float* __restrict__ stm,
    float* __restrict__ corr, float* __restrict__ vel,
    float* __restrict__ vphi, float* __restrict__ vstr)
{
    int bid = blockIdx.x;
    if (bid < CORR_NWG) {
        corr_body(bid, prev, nxt, corr);
    } else if (bid < CORR_NWG + VELM_NWG) {
        velm_body(bid - CORR_NWG, phi, stm, vel, vphi, vstr);
    } else {
        velt_body(bid - CORR_NWG - VELM_NWG, phi, stm, vel, vphi, vstr);
    }
}

extern "C" void kernel_launch(void* const* d_in, const int* in_sizes, int n_in,
                              void* d_out, int out_size, void* d_ws, size_t ws_size,
                              hipStream_t stream)
{
    const float* prev = (const float*)d_in[0];
    const float* nxt  = (const float*)d_in[1];
    const float* phi  = (const float*)d_in[2];
    const float* stm  = (const float*)d_in[3];

    float* out = (float*)d_out;
    const size_t corr_sz = (size_t)CB * 27 * CX * CY * CZ;   // 23,887,872
    const size_t vel_sz  = (size_t)CB * 3 * O * O * O;       // 19,934,016
    float* corr = out;
    float* vel  = out + corr_sz;
    float* vphi = vel + vel_sz;
    float* vstr = vphi + vel_sz;

    fused_kernel<<<CORR_NWG + VELM_NWG + VELT_NWG, 256, 0, stream>>>(
        prev, nxt, phi, stm, corr, vel, vphi, vstr);
}

// Round 13
// 211.223 us; speedup vs baseline: 1.0039x; 1.0005x over previous
//
#include <hip/hip_runtime.h>

// Shapes (fixed):
//   prev/next: [8, 32, 48, 48, 48] f32
//   phi:       [8, 1, 96, 96, 96] f32
//   stream:    [8, 3, 96, 96, 96] f32
// Outputs concatenated in d_out (f32): corr [8,27,48^3], vel/vel_phi/vel_stream [8,3,94^3]
//
// Model v4: wall = wave-vmem instruction issue (~24cy) + HBM-RMW penalty for
// partially-written 32B sectors under nt stores (velm/velt split left an 8B
// hole per row filled ~100us later: +35MB FETCH). R13 = R12's full-row
// blocks with the OOB fix: output offset uses (i,j) only, batch via (b*3+c).
// Lanes 0..229: 10 rows x t=0..91 (4-wide aligned). Lanes 230..239: the
// t=92,93 pair of the same 10 rows. corr = R8 unchanged.

typedef float f2 __attribute__((ext_vector_type(2)));
typedef float f4 __attribute__((ext_vector_type(4)));
typedef float f4u __attribute__((ext_vector_type(4), aligned(8)));

constexpr int CB = 8, CC = 32, CX = 48, CY = 48, CZ = 48;
constexpr int H = 96, O = 94;
constexpr int PLANE = CY * CZ;       // 2304
constexpr int CSTR  = CX * PLANE;    // 110592
constexpr int HP    = H * H;         // 9216
constexpr size_t O3 = (size_t)O * O * O;

constexpr int CORR_NWG   = (CB * CX * CY * (CZ / 4)) / 256;   // 864
constexpr int ROWS_TOTAL = CB * O * O;                        // 70,688 output rows
constexpr int RPB        = 10;                                // rows per block
constexpr int VELM_NWG   = (ROWS_TOTAL + RPB - 1) / RPB;      // 7069

// ---------------------------------------------------------------------------
// corr (R8, unchanged): thread owns (b,x,y,z4*4..+3); 10 f4 loads per c-step.
// ---------------------------------------------------------------------------
__device__ __forceinline__ void corr_body(
    int bid, const float* __restrict__ prev, const float* __restrict__ nxt,
    float* __restrict__ corr)
{
    constexpr int Z4 = CZ / 4;                       // 12
    int swz = (bid & 7) * (CORR_NWG / 8) + (bid >> 3);
    int idx = swz * 256 + (int)threadIdx.x;
    int z4 = idx % Z4; int r = idx / Z4;
    int y = r % CY; r /= CY;
    int x = r % CX; int b = r / CX;

    const size_t bbase = (size_t)b * CC * CSTR;
    const float* __restrict__ nbase = nxt + bbase;
    const float* pp = prev + bbase + (size_t)x * PLANE + (size_t)y * CZ + z4 * 4;

    const float* tp[9];
    float scj[9];
#pragma unroll
    for (int a = 0; a < 3; ++a) {
        int xx = x + a - 1;
        bool vx = (unsigned)xx < (unsigned)CX;
#pragma unroll
        for (int d = 0; d < 3; ++d) {
            int yy = y + d - 1;
            bool ok = vx && ((unsigned)yy < (unsigned)CY);
            tp[a * 3 + d] = nbase + (size_t)(ok ? xx : x) * PLANE
                                  + (size_t)(ok ? yy : y) * CZ + z4 * 4;
            scj[a * 3 + d] = ok ? (1.0f / 32.0f) : 0.0f;
        }
    }

    f4 acc[9];
#pragma unroll
    for (int jj = 0; jj < 9; ++jj) acc[jj] = f4{0.f, 0.f, 0.f, 0.f};

#pragma unroll 2
    for (int c = 0; c < CC; ++c) {
        f4 pv = *reinterpret_cast<const f4*>(pp);
#pragma unroll
        for (int jj = 0; jj < 9; ++jj) {
            f4 nv = *reinterpret_cast<const f4*>(tp[jj]);
            acc[jj] += pv * nv;
            tp[jj] += CSTR;
        }
        pp += CSTR;
    }

    const size_t obase = (size_t)b * 27 * CSTR + (size_t)x * PLANE
                       + (size_t)y * CZ + z4 * 4;
#pragma unroll
    for (int jj = 0; jj < 9; ++jj) {
        f4 v = acc[jj] * scj[jj];
        f4 gm = v; if (z4 == Z4 - 1) gm.w = 0.f;     // k=-1: zero z==47
        f4 gp = v; if (z4 == 0)      gp.x = 0.f;     // k=+1: zero z==0
        __builtin_nontemporal_store(gm, (f4*)(corr + obase + (size_t)jj * CSTR));
        __builtin_nontemporal_store(v,  (f4*)(corr + obase + (size_t)(9 + jj) * CSTR));
        __builtin_nontemporal_store(gp, (f4*)(corr + obase + (size_t)(18 + jj) * CSTR));
    }
}

// Row helpers — all loads naturally aligned (base 16B-aligned at t%4==0).
struct R6 { f4 a; f2 b; };     // elems 0..5
struct R5 { f4 a; float e; };  // elems 0..4
__device__ __forceinline__ R6 ld6(const float* p) {
    R6 r; r.a = *reinterpret_cast<const f4*>(p);
    r.b = *reinterpret_cast<const f2*>(p + 4); return r;
}
__device__ __forceinline__ R5 ld5(const float* p) {
    R5 r; r.a = *reinterpret_cast<const f4*>(p); r.e = p[4]; return r;
}
#define E6(r, k) ((k) < 4 ? (r).a[(k)] : (r).b[(k) - 4])
#define E5(r, k) ((k) < 4 ? (r).a[(k)] : (r).e)

__device__ __forceinline__ void velm_body(
    int bid, const float* __restrict__ phi, const float* __restrict__ stm,
    float* __restrict__ vel, float* __restrict__ vphi, float* __restrict__ vstr)
{
    const int q = VELM_NWG >> 3, rr = VELM_NWG & 7;  // 883, 5
    int xcd = bid & 7, g = bid >> 3;
    int swz = (xcd < rr) ? (xcd * (q + 1) + g) : (rr * (q + 1) + (xcd - rr) * q + g);
    const int rowbase = swz * RPB;
    const int tid = (int)threadIdx.x;
    const size_t hc = (size_t)H * HP;

    if (tid < 230) {
        // ---- path A: 4 outputs at t = 4*tt, tt = 0..22 ----
        int r = tid / 23, tt = tid % 23;
        int row = rowbase + r;
        if (row >= ROWS_TOTAL) return;
        int j = row % O; int tmp = row / O;
        int i = tmp % O; int b = tmp / O;
        const int t = 4 * tt;

        const float* ph = phi + (size_t)b * hc;
        const float* s0 = stm + (size_t)b * 3 * hc;
        const float* s1 = s0 + hc;
        const float* s2 = s1 + hc;
        const size_t ctr = (size_t)(i + 1) * HP + (size_t)(j + 1) * H + t;
        const size_t oo = ((size_t)i * O + j) * O + t;      // batch via (b3+c)*O3
        const size_t b3 = (size_t)b * 3;

        // phi phase
        R6 c11 = ld6(ph + ctr);
        R5 r12 = ld5(ph + ctr + H);
        R5 r10 = ld5(ph + ctr - H);
        R5 r21 = ld5(ph + ctr + HP);
        R5 r01 = ld5(ph + ctr - HP);
        float mup[4], mvp[4], mwp[4];
#pragma unroll
        for (int o = 0; o < 4; ++o) {
            mup[o] = (E6(c11, o + 2) - E6(c11, o)) * 0.5f;
            mvp[o] = (E5(r12, o + 1) - E5(r10, o + 1)) * 0.5f;
            mwp[o] = (E5(r21, o + 1) - E5(r01, o + 1)) * 0.5f;
        }
        __builtin_nontemporal_store(f4u{mup[0], mup[1], mup[2], mup[3]}, (f4u*)(vphi + (b3 + 0) * O3 + oo));
        __builtin_nontemporal_store(f4u{mvp[0], mvp[1], mvp[2], mvp[3]}, (f4u*)(vphi + (b3 + 1) * O3 + oo));
        __builtin_nontemporal_store(f4u{mwp[0], mwp[1], mwp[2], mwp[3]}, (f4u*)(vphi + (b3 + 2) * O3 + oo));

        // u = d_x s1 - d_y s0
        R5 A1_21 = ld5(s1 + ctr + HP);
        R6 A1_11 = ld6(s1 + ctr);
        R5 A0_12 = ld5(s0 + ctr + H);
        R6 A0_11 = ld6(s0 + ctr);
        float u[5];
#pragma unroll
        for (int k = 0; k < 5; ++k)
            u[k] = (E5(A1_21, k) - E6(A1_11, k)) - (E5(A0_12, k) - E6(A0_11, k));
        float mus[4];
#pragma unroll
        for (int o = 0; o < 4; ++o) mus[o] = (u[o + 1] + u[o]) * 0.5f;
        __builtin_nontemporal_store(f4u{mus[0], mus[1], mus[2], mus[3]}, (f4u*)(vstr + (b3 + 0) * O3 + oo));
        __builtin_nontemporal_store(f4u{mup[0] + mus[0], mup[1] + mus[1], mup[2] + mus[2], mup[3] + mus[3]},
                                    (f4u*)(vel + (b3 + 0) * O3 + oo));

        // v = d_t s0 - d_x s2
        R6 B0_10 = ld6(s0 + ctr - H);
        R5 B2_21 = ld5(s2 + ctr + HP);
        R5 B2_11 = ld5(s2 + ctr);
        R5 B2_20 = ld5(s2 + ctr + HP - H);
        R5 B2_10 = ld5(s2 + ctr - H);
        float mvs[4];
#pragma unroll
        for (int o = 0; o < 4; ++o) {
            float v1 = (E6(A0_11, o + 2) - E6(A0_11, o + 1)) - (E5(B2_21, o + 1) - E5(B2_11, o + 1));
            float v0 = (E6(B0_10, o + 2) - E6(B0_10, o + 1)) - (E5(B2_20, o + 1) - E5(B2_10, o + 1));
            mvs[o] = (v1 + v0) * 0.5f;
        }
        __builtin_nontemporal_store(f4u{mvs[0], mvs[1], mvs[2], mvs[3]}, (f4u*)(vstr + (b3 + 1) * O3 + oo));
        __builtin_nontemporal_store(f4u{mvp[0] + mvs[0], mvp[1] + mvs[1], mvp[2] + mvs[2], mvp[3] + mvs[3]},
                                    (f4u*)(vel + (b3 + 1) * O3 + oo));

        // w = d_y s2 - d_t s1
        R5 C2_12 = ld5(s2 + ctr + H);
        R5 C2_02 = ld5(s2 + ctr - HP + H);
        R5 C2_01 = ld5(s2 + ctr - HP);
        R6 C1_01 = ld6(s1 + ctr - HP);
        float mws[4];
#pragma unroll
        for (int o = 0; o < 4; ++o) {
            float w1 = (E5(C2_12, o + 1) - E5(B2_11, o + 1)) - (E6(A1_11, o + 2) - E6(A1_11, o + 1));
            float w0 = (E5(C2_02, o + 1) - E5(C2_01, o + 1)) - (E6(C1_01, o + 2) - E6(C1_01, o + 1));
            mws[o] = (w1 + w0) * 0.5f;
        }
        __builtin_nontemporal_store(f4u{mws[0], mws[1], mws[2], mws[3]}, (f4u*)(vstr + (b3 + 2) * O3 + oo));
        __builtin_nontemporal_store(f4u{mwp[0] + mws[0], mwp[1] + mws[1], mwp[2] + mws[2], mwp[3] + mws[3]},
                                    (f4u*)(vel + (b3 + 2) * O3 + oo));
    } else if (tid < 240) {
        // ---- path B: t = 92,93 for one row; window 92..95 = one f4 per tap row ----
        int row = rowbase + (tid - 230);
        if (row >= ROWS_TOTAL) return;
        int j = row % O; int tmp = row / O;
        int i = tmp % O; int b = tmp / O;
        const int t = 92;

        const float* ph = phi + (size_t)b * hc;
        const float* s0 = stm + (size_t)b * 3 * hc;
        const float* s1 = s0 + hc;
        const float* s2 = s1 + hc;
        const size_t ctr = (size_t)(i + 1) * HP + (size_t)(j + 1) * H + t;

#define L4(p) (*reinterpret_cast<const f4*>(p))
        f4 c11 = L4(ph + ctr), r12 = L4(ph + ctr + H), r10 = L4(ph + ctr - H);
        f4 r21 = L4(ph + ctr + HP), r01 = L4(ph + ctr - HP);
        f4 b1_21 = L4(s1 + ctr + HP), b1_11 = L4(s1 + ctr), b1_01 = L4(s1 + ctr - HP);
        f4 b0_12 = L4(s0 + ctr + H), b0_11 = L4(s0 + ctr), b0_10 = L4(s0 + ctr - H);
        f4 b2_21 = L4(s2 + ctr + HP), b2_11 = L4(s2 + ctr), b2_20 = L4(s2 + ctr + HP - H);
        f4 b2_10 = L4(s2 + ctr - H), b2_12 = L4(s2 + ctr + H), b2_02 = L4(s2 + ctr - HP + H);
        f4 b2_01 = L4(s2 + ctr - HP);
#undef L4

        float mup[2], mvp[2], mwp[2], mus[2], mvs[2], mws[2];
        float u[3];
#pragma unroll
        for (int k = 0; k < 3; ++k)
            u[k] = (b1_21[k] - b1_11[k]) - (b0_12[k] - b0_11[k]);
#pragma unroll
        for (int o = 0; o < 2; ++o) {
            mup[o] = (c11[o + 2] - c11[o]) * 0.5f;
            mvp[o] = (r12[o + 1] - r10[o + 1]) * 0.5f;
            mwp[o] = (r21[o + 1] - r01[o + 1]) * 0.5f;
            mus[o] = (u[o + 1] + u[o]) * 0.5f;
            float v1 = (b0_11[o + 2] - b0_11[o + 1]) - (b2_21[o + 1] - b2_11[o + 1]);
            float v0 = (b0_10[o + 2] - b0_10[o + 1]) - (b2_20[o + 1] - b2_10[o + 1]);
            mvs[o] = (v1 + v0) * 0.5f;
            float w1 = (b2_12[o + 1] - b2_11[o + 1]) - (b1_11[o + 2] - b1_11[o + 1]);
            float w0 = (b2_02[o + 1] - b2_01[o + 1]) - (b1_01[o + 2] - b1_01[o + 1]);
            mws[o] = (w1 + w0) * 0.5f;
        }

        const size_t oo = ((size_t)i * O + j) * O + t;      // batch via (b3+c)*O3
        const size_t b3 = (size_t)b * 3;
        __builtin_nontemporal_store(f2{mup[0], mup[1]}, (f2*)(vphi + (b3 + 0) * O3 + oo));
        __builtin_nontemporal_store(f2{mvp[0], mvp[1]}, (f2*)(vphi + (b3 + 1) * O3 + oo));
        __builtin_nontemporal_store(f2{mwp[0], mwp[1]}, (f2*)(vphi + (b3 + 2) * O3 + oo));
        __builtin_nontemporal_store(f2{mus[0], mus[1]}, (f2*)(vstr + (b3 + 0) * O3 + oo));
        __builtin_nontemporal_store(f2{mvs[0], mvs[1]}, (f2*)(vstr + (b3 + 1) * O3 + oo));
        __builtin_nontemporal_store(f2{mws[0], mws[1]}, (f2*)(vstr + (b3 + 2) * O3 + oo));
        __builtin_nontemporal_store(f2{mup[0] + mus[0], mup[1] + mus[1]}, (f2*)(vel + (b3 + 0) * O3 + oo));
        __builtin_nontemporal_store(f2{mvp[0] + mvs[0], mvp[1] + mvs[1]}, (f2*)(vel + (b3 + 1) * O3 + oo));
        __builtin_nontemporal_store(f2{mwp[0] + mws[0], mwp[1] + mws[1]}, (f2*)(vel + (b3 + 2) * O3 + oo));
    }
}

__global__ __launch_bounds__(256) void fused_kernel(
    const float* __restrict__ prev, const float* __restrict__ nxt,
    const float* __restrict__ phi, const float* __restrict__ stm,
    float* __restrict__ corr, float* __restrict__ vel,
    float* __restrict__ vphi, float* __restrict__ vstr)
{
    int bid = blockIdx.x;
    if (bid < CORR_NWG) {
        corr_body(bid, prev, nxt, corr);
    } else {
        velm_body(bid - CORR_NWG, phi, stm, vel, vphi, vstr);
    }
}

extern "C" void kernel_launch(void* const* d_in, const int* in_sizes, int n_in,
                              void* d_out, int out_size, void* d_ws, size_t ws_size,
                              hipStream_t stream)
{
    const float* prev = (const float*)d_in[0];
    const float* nxt  = (const float*)d_in[1];
    const float* phi  = (const float*)d_in[2];
    const float* stm  = (const float*)d_in[3];

    float* out = (float*)d_out;
    const size_t corr_sz = (size_t)CB * 27 * CX * CY * CZ;   // 23,887,872
    const size_t vel_sz  = (size_t)CB * 3 * O * O * O;       // 19,934,016
    float* corr = out;
    float* vel  = out + corr_sz;
    float* vphi = vel + vel_sz;
    float* vstr = vphi + vel_sz;

    fused_kernel<<<CORR_NWG + VELM_NWG, 256, 0, stream>>>(
        prev, nxt, phi, stm, corr, vel, vphi, vstr);
}

// Round 14
// 173.349 us; speedup vs baseline: 1.2232x; 1.2185x over previous
//
#include <hip/hip_runtime.h>

// Shapes (fixed):
//   prev/next: [8, 32, 48, 48, 48] f32
//   phi:       [8, 1, 96, 96, 96] f32
//   stream:    [8, 3, 96, 96, 96] f32
// Outputs concatenated in d_out (f32): corr [8,27,48^3], vel/vel_phi/vel_stream [8,3,94^3]
//
// R14 = R8 verbatim (best measured: 171.4 us). Record of the search:
//  - corr f4 z-granule-4 (R8): 10 loads / 4 sites, clamped taps + epilogue
//    zero-scale; 864 blocks, batch-per-XCD swizzle. Confirmed win (+37us vs f2).
//  - vel f2 2-wide (R3/R8): 45 vmem / 2 outputs, 12978 blocks. Empirically
//    optimal: 4-wide variants (R9/R10/R11/R13) all 205-212us regardless of
//    alignment/store-width/tail-fusion -- per-thread vmem bursts defeat the
//    instruction-count savings (queue saturation / fewer waves).
//  - nt stores: wall-best (R5 A/B); output traffic at ideal 337MB.
//  - LDS staging (R7), sw prefetch (R6), wide-unaligned (R9): all regressions.

typedef float f2 __attribute__((ext_vector_type(2)));
typedef float f4 __attribute__((ext_vector_type(4)));

constexpr int CB = 8, CC = 32, CX = 48, CY = 48, CZ = 48;
constexpr int H = 96, O = 94;
constexpr int PLANE = CY * CZ;       // 2304
constexpr int CSTR  = CX * PLANE;    // 110592

constexpr int CORR_NWG = (CB * CX * CY * (CZ / 4)) / 256;    // 864
constexpr int VEL_TOTAL = CB * O * O * (O / 2);              // 3,322,336
constexpr int VEL_NWG = (VEL_TOTAL + 255) / 256;             // 12978

__device__ __forceinline__ void corr_body(
    int bid, const float* __restrict__ prev, const float* __restrict__ nxt,
    float* __restrict__ corr)
{
    constexpr int Z4 = CZ / 4;                       // 12
    int swz = (bid & 7) * (CORR_NWG / 8) + (bid >> 3);  // XCD-chunked (864%8==0)
    int idx = swz * 256 + (int)threadIdx.x;
    int z4 = idx % Z4; int r = idx / Z4;
    int y = r % CY; r /= CY;
    int x = r % CX; int b = r / CX;

    const size_t bbase = (size_t)b * CC * CSTR;
    const float* __restrict__ nbase = nxt + bbase;

    const float* pp = prev + bbase + (size_t)x * PLANE + (size_t)y * CZ + z4 * 4;

    const float* tp[9];
    float scj[9];
#pragma unroll
    for (int a = 0; a < 3; ++a) {
        int xx = x + a - 1;
        bool vx = (unsigned)xx < (unsigned)CX;
#pragma unroll
        for (int d = 0; d < 3; ++d) {
            int yy = y + d - 1;
            bool ok = vx && ((unsigned)yy < (unsigned)CY);
            // invalid taps read a safe clamped address; zeroed by scj at the end
            tp[a * 3 + d] = nbase + (size_t)(ok ? xx : x) * PLANE
                                  + (size_t)(ok ? yy : y) * CZ + z4 * 4;
            scj[a * 3 + d] = ok ? (1.0f / 32.0f) : 0.0f;
        }
    }

    f4 acc[9];
#pragma unroll
    for (int jj = 0; jj < 9; ++jj) acc[jj] = f4{0.f, 0.f, 0.f, 0.f};

#pragma unroll 2
    for (int c = 0; c < CC; ++c) {
        f4 pv = *reinterpret_cast<const f4*>(pp);
#pragma unroll
        for (int jj = 0; jj < 9; ++jj) {
            f4 nv = *reinterpret_cast<const f4*>(tp[jj]);
            acc[jj] += pv * nv;
            tp[jj] += CSTR;
        }
        pp += CSTR;
    }

    const size_t obase = (size_t)b * 27 * CSTR + (size_t)x * PLANE
                       + (size_t)y * CZ + z4 * 4;
#pragma unroll
    for (int jj = 0; jj < 9; ++jj) {
        f4 v = acc[jj] * scj[jj];
        f4 gm = v; if (z4 == Z4 - 1) gm.w = 0.f;     // k=-1: zero z==47
        f4 gp = v; if (z4 == 0)      gp.x = 0.f;     // k=+1: zero z==0
        __builtin_nontemporal_store(gm, (f4*)(corr + obase + (size_t)jj * CSTR));
        __builtin_nontemporal_store(v,  (f4*)(corr + obase + (size_t)(9 + jj) * CSTR));
        __builtin_nontemporal_store(gp, (f4*)(corr + obase + (size_t)(18 + jj) * CSTR));
    }
}

__device__ __forceinline__ void vel_body(
    int bid, const float* __restrict__ phi, const float* __restrict__ stm,
    float* __restrict__ vel, float* __restrict__ vphi, float* __restrict__ vstr)
{
    constexpr int TT = O / 2;                        // 47
    const int q = VEL_NWG >> 3, rr = VEL_NWG & 7;    // 1622, 2
    int xcd = bid & 7, g = bid >> 3;
    int swz = (xcd < rr) ? (xcd * (q + 1) + g) : (rr * (q + 1) + (xcd - rr) * q + g);
    int idx = swz * 256 + (int)threadIdx.x;
    if (idx >= VEL_TOTAL) return;
    int tt = idx % TT; int r2 = idx / TT;
    int j = r2 % O; r2 /= O;
    int i = r2 % O; int b = r2 / O;
    const int t = tt * 2;

    const int hp = H * H;                            // 9216
    const size_t hc = (size_t)H * hp;
    const float* ph = phi + (size_t)b * hc;
    const float* s0 = stm + (size_t)b * 3 * hc;
    const float* s1 = s0 + hc;
    const float* s2 = s1 + hc;

#define R(A, B_) ((size_t)(A) * hp + (size_t)(B_) * H + t)

    // ---- phi taps ----
    const float* p11 = ph + R(i + 1, j + 1);
    f2 p11a = *(const f2*)p11;           // t, t+1
    f2 p11b = *(const f2*)(p11 + 2);     // t+2, t+3
    float p12_1 = ph[R(i + 1, j + 2) + 1], p12_2 = ph[R(i + 1, j + 2) + 2];
    float p10_1 = ph[R(i + 1, j)     + 1], p10_2 = ph[R(i + 1, j)     + 2];
    float p21_1 = ph[R(i + 2, j + 1) + 1], p21_2 = ph[R(i + 2, j + 1) + 2];
    float p01_1 = ph[R(i,     j + 1) + 1], p01_2 = ph[R(i,     j + 1) + 2];

    float pc0 = p11a.y, pc1 = p11b.x;
    float mup0 = ((p11b.x - pc0) + (pc0 - p11a.x)) * 0.5f;
    float mup1 = ((p11b.y - pc1) + (pc1 - p11a.y)) * 0.5f;
    float mvp0 = ((p12_1 - pc0) + (pc0 - p10_1)) * 0.5f;
    float mvp1 = ((p12_2 - pc1) + (pc1 - p10_2)) * 0.5f;
    float mwp0 = ((p21_1 - pc0) + (pc0 - p01_1)) * 0.5f;
    float mwp1 = ((p21_2 - pc1) + (pc1 - p01_2)) * 0.5f;

    // ---- stream taps ----
    const float* q1_11 = s1 + R(i + 1, j + 1);
    f2 s1_11a = *(const f2*)q1_11;  f2 s1_11b = *(const f2*)(q1_11 + 2);
    const float* q1_21 = s1 + R(i + 2, j + 1);
    f2 s1_21a = *(const f2*)q1_21;  float s1_21_2 = q1_21[2];
    const float* q1_01 = s1 + R(i, j + 1);
    float s1_01_1 = q1_01[1];       f2 s1_01b = *(const f2*)(q1_01 + 2);

    const float* q0_11 = s0 + R(i + 1, j + 1);
    f2 s0_11a = *(const f2*)q0_11;  f2 s0_11b = *(const f2*)(q0_11 + 2);
    const float* q0_12 = s0 + R(i + 1, j + 2);
    f2 s0_12a = *(const f2*)q0_12;  float s0_12_2 = q0_12[2];
    const float* q0_10 = s0 + R(i + 1, j);
    float s0_10_1 = q0_10[1];       f2 s0_10b = *(const f2*)(q0_10 + 2);

    float s2_21_1 = s2[R(i + 2, j + 1) + 1], s2_21_2 = s2[R(i + 2, j + 1) + 2];
    float s2_11_1 = s2[R(i + 1, j + 1) + 1], s2_11_2 = s2[R(i + 1, j + 1) + 2];
    float s2_20_1 = s2[R(i + 2, j)     + 1], s2_20_2 = s2[R(i + 2, j)     + 2];
    float s2_10_1 = s2[R(i + 1, j)     + 1], s2_10_2 = s2[R(i + 1, j)     + 2];
    float s2_12_1 = s2[R(i + 1, j + 2) + 1], s2_12_2 = s2[R(i + 1, j + 2) + 2];
    float s2_02_1 = s2[R(i,     j + 2) + 1], s2_02_2 = s2[R(i,     j + 2) + 2];
    float s2_01_1 = s2[R(i,     j + 1) + 1], s2_01_2 = s2[R(i,     j + 1) + 2];
#undef R

    // u = d_x s1 - d_y s0 ; mu = (u(t+1)+u(t))/2
    float u0 = (s1_21a.x - s1_11a.x) - (s0_12a.x - s0_11a.x);
    float u1 = (s1_21a.y - s1_11a.y) - (s0_12a.y - s0_11a.y);
    float u2 = (s1_21_2  - s1_11b.x) - (s0_12_2  - s0_11b.x);
    float mus0 = (u1 + u0) * 0.5f;
    float mus1 = (u2 + u1) * 0.5f;

    // v = d_t s0 - d_x s2 ; mv = (v(j+1)+v(j))/2
    float v1_0 = (s0_11b.x - s0_11a.y) - (s2_21_1 - s2_11_1);
    float v0_0 = (s0_10b.x - s0_10_1)  - (s2_20_1 - s2_10_1);
    float mvs0 = (v1_0 + v0_0) * 0.5f;
    float v1_1 = (s0_11b.y - s0_11b.x) - (s2_21_2 - s2_11_2);
    float v0_1 = (s0_10b.y - s0_10b.x) - (s2_20_2 - s2_10_2);
    float mvs1 = (v1_1 + v0_1) * 0.5f;

    // w = d_y s2 - d_t s1 ; mw = (w(i+1)+w(i))/2
    float w1_0 = (s2_12_1 - s2_11_1) - (s1_11b.x - s1_11a.y);
    float w0_0 = (s2_02_1 - s2_01_1) - (s1_01b.x - s1_01_1);
    float mws0 = (w1_0 + w0_0) * 0.5f;
    float w1_1 = (s2_12_2 - s2_11_2) - (s1_11b.y - s1_11b.x);
    float w0_1 = (s2_02_2 - s2_01_2) - (s1_01b.y - s1_01b.x);
    float mws1 = (w1_1 + w0_1) * 0.5f;

    const size_t oc = (size_t)O * O * O;
    const size_t o  = ((size_t)i * O + j) * O + t;
    const size_t b3 = (size_t)b * 3;
    __builtin_nontemporal_store(f2{mup0, mup1}, (f2*)(vphi + (b3 + 0) * oc + o));
    __builtin_nontemporal_store(f2{mvp0, mvp1}, (f2*)(vphi + (b3 + 1) * oc + o));
    __builtin_nontemporal_store(f2{mwp0, mwp1}, (f2*)(vphi + (b3 + 2) * oc + o));
    __builtin_nontemporal_store(f2{mus0, mus1}, (f2*)(vstr + (b3 + 0) * oc + o));
    __builtin_nontemporal_store(f2{mvs0, mvs1}, (f2*)(vstr + (b3 + 1) * oc + o));
    __builtin_nontemporal_store(f2{mws0, mws1}, (f2*)(vstr + (b3 + 2) * oc + o));
    __builtin_nontemporal_store(f2{mup0 + mus0, mup1 + mus1}, (f2*)(vel + (b3 + 0) * oc + o));
    __builtin_nontemporal_store(f2{mvp0 + mvs0, mvp1 + mvs1}, (f2*)(vel + (b3 + 1) * oc + o));
    __builtin_nontemporal_store(f2{mwp0 + mws0, mwp1 + mws1}, (f2*)(vel + (b3 + 2) * oc + o));
}

__global__ __launch_bounds__(256) void fused_kernel(
    const float* __restrict__ prev, const float* __restrict__ nxt,
    const float* __restrict__ phi, const float* __restrict__ stm,
    float* __restrict__ corr, float* __restrict__ vel,
    float* __restrict__ vphi, float* __restrict__ vstr)
{
    int bid = blockIdx.x;
    if (bid < CORR_NWG) {
        corr_body(bid, prev, nxt, corr);
    } else {
        vel_body(bid - CORR_NWG, phi, stm, vel, vphi, vstr);
    }
}

extern "C" void kernel_launch(void* const* d_in, const int* in_sizes, int n_in,
                              void* d_out, int out_size, void* d_ws, size_t ws_size,
                              hipStream_t stream)
{
    const float* prev = (const float*)d_in[0];
    const float* nxt  = (const float*)d_in[1];
    const float* phi  = (const float*)d_in[2];
    const float* stm  = (const float*)d_in[3];

    float* out = (float*)d_out;
    const size_t corr_sz = (size_t)CB * 27 * CX * CY * CZ;   // 23,887,872
    const size_t vel_sz  = (size_t)CB * 3 * O * O * O;       // 19,934,016
    float* corr = out;
    float* vel  = out + corr_sz;
    float* vphi = vel + vel_sz;
    float* vstr = vphi + vel_sz;

    fused_kernel<<<CORR_NWG + VEL_NWG, 256, 0, stream>>>(
        prev, nxt, phi, stm, corr, vel, vphi, vstr);
}